// Round 8
// baseline (169.320 us; speedup 1.0000x reference)
//
#include <hip/hip_runtime.h>
#include <stdint.h>

// B=32, C=256, H=W=32 (HW=1024), GROUPS=32, EPS=1e-5.
// K0 wprep : Wt[d][c] = gs[c]*W[c][d]*scale (bf16); bias[d]=(b[d]+sum_c gb[c]W[c][d])*scale
//            q-scale = log2(e)/16  (folds softmax 1/sqrt(C) AND exp->exp2 domain)
// K1 gn    : Xh[b][p][c] = (x-mu)*rsqrt(var+eps) (bf16)
// K2 gemmNT: shared B-tile staged via global_load_lds, XOR-swizzled
// K3 attn<NH=2>: 32x32x16 MFMA, swapped QK (S^T), lane-local softmax, P in regs.
//            K TRIPLE-buffered (2-step prefetch), V double-buffered (1-step),
//            LDS 80KB = 2 blocks/CU. Loop barrier = s_waitcnt vmcnt(4)+s_barrier
//            (counted vmcnt: K(t+2) loads stay in flight across the barrier).
// K3b merge: combine halves (in-place into O0)
// K4 gemmNT: out = x + Wo^T O + bo (fp32)

#define NB 32
#define CH 256
#define HWPX 1024

typedef __bf16 bf16x8 __attribute__((ext_vector_type(8)));
typedef float f32x4 __attribute__((ext_vector_type(4)));
typedef float f32x16 __attribute__((ext_vector_type(16)));
typedef unsigned short u16;
typedef unsigned int u32;
typedef u16 u16x4 __attribute__((ext_vector_type(4)));
typedef u16 u16x8 __attribute__((ext_vector_type(8)));
typedef u32 u32x4 __attribute__((ext_vector_type(4)));

__device__ __forceinline__ u16 f2bf(float f) {
    __bf16 h = (__bf16)f;
    return __builtin_bit_cast(u16, h);
}
__device__ __forceinline__ float bf2f(u16 u) {
    union { unsigned int u; float f; } v; v.u = ((unsigned int)u) << 16;
    return v.f;
}
__device__ __forceinline__ u32 pk2(float a, float b) {
    return ((u32)f2bf(b) << 16) | (u32)f2bf(a);
}
__device__ __forceinline__ bf16x8 ldb8(const u16* p) {
    return __builtin_bit_cast(bf16x8, *(const u16x8*)p);
}
__device__ __forceinline__ void gld_lds16(const u16* g, u16* l) {
    __builtin_amdgcn_global_load_lds(
        (const __attribute__((address_space(1))) void*)g,
        (__attribute__((address_space(3))) void*)l, 16, 0, 0);
}

// ---------------- K0: weight prep ----------------
__global__ __launch_bounds__(256) void wprep(
    const float* __restrict__ Wq, const float* __restrict__ bq,
    const float* __restrict__ gqs, const float* __restrict__ gqb,
    const float* __restrict__ Wk, const float* __restrict__ bk,
    const float* __restrict__ gks, const float* __restrict__ gkb,
    const float* __restrict__ Wv, const float* __restrict__ bv,
    const float* __restrict__ gvs, const float* __restrict__ gvb,
    const float* __restrict__ Wo, const float* __restrict__ bo,
    u16* __restrict__ Wt, float* __restrict__ bias)
{
    int m = blockIdx.x >> 8;
    int d = blockIdx.x & 255;
    int c = threadIdx.x;
    const float *W, *bb, *gs, *gb; float scale;
    const float QSC = 0.09016844005556021f;   // log2(e)/16
    if (m == 0)      { W = Wq; bb = bq; gs = gqs; gb = gqb; scale = QSC; }
    else if (m == 1) { W = Wk; bb = bk; gs = gks; gb = gkb; scale = 1.f; }
    else if (m == 2) { W = Wv; bb = bv; gs = gvs; gb = gvb; scale = 1.f; }
    else             { W = Wo; bb = bo; gs = nullptr; gb = nullptr; scale = 1.f; }
    float w   = W[c * 256 + d];
    float gsc = gs ? gs[c] : 1.f;
    float gbc = gb ? gb[c] : 0.f;
    Wt[((size_t)m << 16) + d * 256 + c] = f2bf(w * gsc * scale);
    __shared__ float red[256];
    red[c] = gbc * w;
    __syncthreads();
    for (int s = 128; s > 0; s >>= 1) { if (c < s) red[c] += red[c + s]; __syncthreads(); }
    if (c == 0) bias[m * 256 + d] = (bb[d] + red[0]) * scale;
}

// ---------------- K1: groupnorm ----------------
__global__ __launch_bounds__(256) void gn_kernel(const float* __restrict__ x,
                                                 u16* __restrict__ Xh)
{
    int blk = blockIdx.x;
    int b = blk >> 5, g = blk & 31;
    const float* base = x + (size_t)(b * 256 + g * 8) * 1024;
    int t = threadIdx.x;
    float s = 0.f, s2 = 0.f;
    for (int i = 0; i < 32; i++) { float v = base[t + i * 256]; s += v; s2 += v * v; }
    __shared__ float rs[256], rq[256];
    rs[t] = s; rq[t] = s2;
    __syncthreads();
    for (int k = 128; k > 0; k >>= 1) {
        if (t < k) { rs[t] += rs[t + k]; rq[t] += rq[t + k]; }
        __syncthreads();
    }
    float mu  = rs[0] * (1.f / 8192.f);
    float var = rq[0] * (1.f / 8192.f) - mu * mu;
    float rv  = rsqrtf(var + 1e-5f);
    u16* outp = Xh + (size_t)b * (HWPX * CH) + g * 8;
    for (int it = 0; it < 4; it++) {
        int p = t + it * 256;
        u16x8 tv;
        #pragma unroll
        for (int c2 = 0; c2 < 8; c2++) tv[c2] = f2bf((base[c2 * 1024 + p] - mu) * rv);
        *(u16x8*)(outp + (size_t)p * 256) = tv;
    }
}

// ---------------- K2/K4: NT GEMM, shared B-tile in LDS ----------------
template <int MODE>
__global__ __launch_bounds__(256) void gemm_nt(
    const u16* __restrict__ A, const u16* __restrict__ Bm,
    const float* __restrict__ bias,
    u16* __restrict__ Cb, float* __restrict__ Cf,
    const float* __restrict__ xres)
{
    __shared__ __align__(16) u16 Bt[64 * 256];
    int tid = threadIdx.x;
    int lane = tid & 63, wave = tid >> 6;
    int m0 = blockIdx.y * 64 + wave * 16;
    int n0 = blockIdx.x * 64;

    #pragma unroll
    for (int i = 0; i < 8; i++) {
        int G = i * 256 + tid;
        int row = G >> 5, g = G & 31;
        const u16* src = Bm + (size_t)(n0 + row) * 256 + ((g ^ (row & 7)) << 3);
        gld_lds16(src, Bt + (size_t)(i * 256 + wave * 64) * 8);
    }

    int lr = lane & 15, hk = lane >> 4, lk = hk * 8;
    int ksw = lr & 7;
    const u16* Ap = A + (size_t)(m0 + lr) * 256 + lk;
    bf16x8 af[8];
    #pragma unroll
    for (int kk = 0; kk < 8; kk++) af[kk] = ldb8(Ap + kk * 32);

    __syncthreads();

    f32x4 acc[4] = {};
    #pragma unroll
    for (int kk = 0; kk < 8; kk++) {
        #pragma unroll
        for (int nt = 0; nt < 4; nt++) {
            int row = nt * 16 + lr;
            int g = (kk * 4 + hk) ^ ksw;
            bf16x8 bf = ldb8(Bt + (size_t)(row * 32 + g) * 8);
            acc[nt] = __builtin_amdgcn_mfma_f32_16x16x32_bf16(af[kk], bf, acc[nt], 0, 0, 0);
        }
    }
    int rbase = m0 + (hk << 2);
    #pragma unroll
    for (int nt = 0; nt < 4; nt++) {
        int col = n0 + nt * 16 + lr;
        #pragma unroll
        for (int j = 0; j < 4; j++) {
            int row = rbase + j;
            float v = acc[nt][j];
            if (MODE == 0) {
                v += bias[col];
                Cb[(size_t)row * 256 + col] = f2bf(v);
            } else {
                int b = col >> 10, p = col & 1023;
                size_t off = (size_t)b * (CH * HWPX) + (size_t)row * 1024 + p;
                v += bias[row];
                if (MODE == 1) Cb[off] = f2bf(v);
                else           Cf[off] = v + xres[off];
            }
        }
    }
}

// ---------------- K3: flash attention, 32x32 MFMA, counted-vmcnt pipeline ----------------
// NH=2: grid 512 (2 blocks/CU), 16 steps; NH=1: grid 256, 32 steps.
// S^T = mfma(A=K, B=Q): lane owns q = q0+(lane&31); PV via in-register P^T frags.
// K: 3 buffers, prefetch distance 2; V: 2 buffers, distance 1.
// Loop barrier: s_waitcnt vmcnt(4) + s_barrier  (K(t+2)'s 4 loads stay in flight).
template <int NH>
__global__ __launch_bounds__(256, 2) void attn(
    const u16* __restrict__ Qt, const u16* __restrict__ Kt,
    const u16* __restrict__ Vc, u16* __restrict__ O0,
    u16* __restrict__ O1, float* __restrict__ ML)
{
    __shared__ __align__(16) u16 Kbuf[3][32 * 256];   // 48 KB, granule ^= kv&7
    __shared__ __align__(16) u16 Vbuf[2][256 * 32];   // 32 KB, granule ^= (c>>1)&3

    int tid = threadIdx.x;
    int lane = tid & 63, wave = tid >> 6;
    int bid = blockIdx.x;
    int b, qb, h;
    if (NH == 2) {
        int x = bid & 7, r = bid >> 3;        // XCD x hosts batches 4x..4x+3
        b  = x * 4 + (r >> 4);
        qb = (r & 15) >> 1;
        h  = r & 1;
    } else {
        b  = (bid & 7) * 4 + (bid >> 6);
        qb = (bid >> 3) & 7;
        h  = 0;
    }
    const int NSTEP = (1024 / NH) / 32;
    int q0 = qb * 128 + wave * 32;

    const u16* Qb = Qt + (size_t)b * (HWPX * CH);
    const u16* Kb = Kt + (size_t)b * (HWPX * CH) + (size_t)h * 512 * 256;
    const u16* Vb = Vc + (size_t)b * (CH * HWPX) + (size_t)h * 512;

    int lq = lane & 31, hi = lane >> 5;
    int kswz = lq & 7;
    int vswz = (lq >> 1) & 3;

    int koff[4], voff[4];
    #pragma unroll
    for (int i = 0; i < 4; i++) {
        int G = i * 256 + tid;
        int kr = G >> 5, kg = G & 31;
        koff[i] = kr * 256 + ((kg ^ (kr & 7)) << 3);
        int vr = G >> 2, vg = G & 3;
        voff[i] = vr * 1024 + ((vg ^ ((vr >> 1) & 3)) << 3);
    }

    bf16x8 qf[16];
    #pragma unroll
    for (int f = 0; f < 16; f++)
        qf[f] = ldb8(Qb + (size_t)(q0 + lq) * 256 + f * 16 + hi * 8);

    f32x16 oa[8] = {};
    float m_run = -1e30f, l_run = 0.f;

    // prologue: stage K(0),V(0); issue K(1); leave K(1) in flight (vmcnt(4))
    #pragma unroll
    for (int i = 0; i < 4; i++)
        gld_lds16(Kb + koff[i], &Kbuf[0][0] + (size_t)(i * 256 + wave * 64) * 8);
    #pragma unroll
    for (int i = 0; i < 4; i++)
        gld_lds16(Vb + voff[i], &Vbuf[0][0] + (size_t)(i * 256 + wave * 64) * 8);
    if (NSTEP > 1) {
        const u16* ks = Kb + (size_t)(32 * 256);
        #pragma unroll
        for (int i = 0; i < 4; i++)
            gld_lds16(ks + koff[i], &Kbuf[1][0] + (size_t)(i * 256 + wave * 64) * 8);
        asm volatile("s_waitcnt vmcnt(4)" ::: "memory");
    } else {
        asm volatile("s_waitcnt vmcnt(0)" ::: "memory");
    }
    __builtin_amdgcn_s_barrier();

    int kcur = 0;
    for (int t = 0; t < NSTEP; ++t) {
        int vcur = t & 1;
        // ---- issue prefetches: V(t+1) first, then K(t+2) (newest 4 = K) ----
        if (t + 1 < NSTEP) {
            const u16* vs = Vb + (t + 1) * 32;
            #pragma unroll
            for (int i = 0; i < 4; i++)
                gld_lds16(vs + voff[i], &Vbuf[vcur ^ 1][0] + (size_t)(i * 256 + wave * 64) * 8);
        }
        if (t + 2 < NSTEP) {
            int knext2 = kcur + 2; if (knext2 >= 3) knext2 -= 3;
            const u16* ks = Kb + (size_t)(t + 2) * (32 * 256);
            #pragma unroll
            for (int i = 0; i < 4; i++)
                gld_lds16(ks + koff[i], &Kbuf[knext2][0] + (size_t)(i * 256 + wave * 64) * 8);
        }

        // ---- QK^T (S^T tile 32kv x 32q), two accumulators ----
        const u16* kb = Kbuf[kcur];
        f32x16 s0 = {}, s1 = {};
        #pragma unroll
        for (int ff = 0; ff < 8; ff++) {
            bf16x8 ka0 = ldb8(kb + (size_t)lq * 256 + (((4 * ff + hi) ^ kswz) << 3));
            s0 = __builtin_amdgcn_mfma_f32_32x32x16_bf16(ka0, qf[2 * ff], s0, 0, 0, 0);
            bf16x8 ka1 = ldb8(kb + (size_t)lq * 256 + (((4 * ff + 2 + hi) ^ kswz) << 3));
            s1 = __builtin_amdgcn_mfma_f32_32x32x16_bf16(ka1, qf[2 * ff + 1], s1, 0, 0, 0);
        }
        float s[16];
        #pragma unroll
        for (int r = 0; r < 16; r++) s[r] = s0[r] + s1[r];

        // ---- lane-local defer-max softmax (log2 domain) ----
        float m01 = fmaxf(s[0], s[1]),   m23 = fmaxf(s[2], s[3]);
        float m45 = fmaxf(s[4], s[5]),   m67 = fmaxf(s[6], s[7]);
        float m89 = fmaxf(s[8], s[9]),   mab = fmaxf(s[10], s[11]);
        float mcd = fmaxf(s[12], s[13]), mef = fmaxf(s[14], s[15]);
        float mloc = fmaxf(fmaxf(fmaxf(m01, m23), fmaxf(m45, m67)),
                           fmaxf(fmaxf(m89, mab), fmaxf(mcd, mef)));
        if (!__all(mloc - m_run <= 4.f)) {
            float mo = fmaxf(mloc, __shfl_xor(mloc, 32));
            float mn = fmaxf(m_run, mo);
            float sc = exp2f(m_run - mn);
            m_run = mn;
            l_run *= sc;
            #pragma unroll
            for (int ct = 0; ct < 8; ct++) {
                #pragma unroll
                for (int r = 0; r < 16; r++) oa[ct][r] *= sc;
            }
        }
        float p[16];
        #pragma unroll
        for (int r = 0; r < 16; r++) p[r] = exp2f(s[r] - m_run);   // <= 2^4
        l_run += (((p[0]+p[1])+(p[2]+p[3]))+((p[4]+p[5])+(p[6]+p[7])))
               + (((p[8]+p[9])+(p[10]+p[11]))+((p[12]+p[13])+(p[14]+p[15])));

        // ---- build P^T B-fragments in-register ----
        u32 w0 = pk2(p[0],  p[1]),  w1 = pk2(p[2],  p[3]);
        u32 w2 = pk2(p[4],  p[5]),  w3 = pk2(p[6],  p[7]);
        u32 w4 = pk2(p[8],  p[9]),  w5 = pk2(p[10], p[11]);
        u32 w6 = pk2(p[12], p[13]), w7 = pk2(p[14], p[15]);
        u32 x0 = (u32)__shfl_xor((int)w0, 32), x1 = (u32)__shfl_xor((int)w1, 32);
        u32 x2 = (u32)__shfl_xor((int)w2, 32), x3 = (u32)__shfl_xor((int)w3, 32);
        u32 x4 = (u32)__shfl_xor((int)w4, 32), x5 = (u32)__shfl_xor((int)w5, 32);
        u32 x6 = (u32)__shfl_xor((int)w6, 32), x7 = (u32)__shfl_xor((int)w7, 32);
        u32x4 pf0 = { hi ? x2 : w0, hi ? x3 : w1, hi ? w2 : x0, hi ? w3 : x1 };
        u32x4 pf1 = { hi ? x6 : w4, hi ? x7 : w5, hi ? w6 : x4, hi ? w7 : x5 };
        bf16x8 pb0 = __builtin_bit_cast(bf16x8, pf0);
        bf16x8 pb1 = __builtin_bit_cast(bf16x8, pf1);

        // ---- PV: oa[ct] += V^T(c,kv) * P^T(kv,q) ----
        const u16* vb = Vbuf[vcur];
        #pragma unroll
        for (int ct = 0; ct < 8; ct++) {
            int row = 32 * ct + lq;
            bf16x8 v0 = ldb8(vb + (size_t)row * 32 + (((hi)     ^ vswz) << 3));
            bf16x8 v1 = ldb8(vb + (size_t)row * 32 + (((2 + hi) ^ vswz) << 3));
            oa[ct] = __builtin_amdgcn_mfma_f32_32x32x16_bf16(v0, pb0, oa[ct], 0, 0, 0);
            oa[ct] = __builtin_amdgcn_mfma_f32_32x32x16_bf16(v1, pb1, oa[ct], 0, 0, 0);
        }

        // ---- counted-vmcnt barrier: only K(t+2)'s 4 loads may stay in flight ----
        if (t + 1 < NSTEP) {
            if (t + 2 < NSTEP) {
                asm volatile("s_waitcnt vmcnt(4)" ::: "memory");
            } else {
                asm volatile("s_waitcnt vmcnt(0)" ::: "memory");
            }
            __builtin_amdgcn_s_barrier();
        }
        kcur = kcur + 1; if (kcur >= 3) kcur -= 3;
    }

    float lt = l_run + __shfl_xor(l_run, 32);
    float rinv = 1.f / lt;
    u16* Ob = ((NH == 2 && h == 1) ? O1 : O0)
              + (size_t)b * (HWPX * CH) + (size_t)(q0 + lq) * 256;
    #pragma unroll
    for (int ct = 0; ct < 8; ct++) {
        #pragma unroll
        for (int rg = 0; rg < 4; rg++) {
            u16x4 st;
            #pragma unroll
            for (int v = 0; v < 4; v++) st[v] = f2bf(oa[ct][rg * 4 + v] * rinv);
            *(u16x4*)(Ob + 32 * ct + 8 * rg + 4 * hi) = st;
        }
    }
    if (NH == 2 && hi == 0) {
        size_t idx = ((size_t)h * 32768 + (size_t)b * 1024 + (q0 + lq)) * 2;
        ML[idx]     = m_run;
        ML[idx + 1] = lt;
    }
}

// ---------------- K3b: merge the two KV-halves (in place into O0) ----------------
__global__ __launch_bounds__(256) void merge_halves(
    u16* __restrict__ O0, const u16* __restrict__ O1, const float* __restrict__ ML)
{
    int gid = blockIdx.x * 256 + threadIdx.x;   // 32 threads per row
    int row = gid >> 5;
    int c8  = (gid & 31) << 3;
    float m0 = ML[row * 2], l0 = ML[row * 2 + 1];
    float m1 = ML[(32768 + row) * 2], l1 = ML[(32768 + row) * 2 + 1];
    float m  = fmaxf(m0, m1);
    float w0 = l0 * exp2f(m0 - m), w1 = l1 * exp2f(m1 - m);
    float inv = 1.f / (w0 + w1);
    w0 *= inv; w1 *= inv;
    u16* p0 = O0 + (size_t)row * 256 + c8;
    const u16* p1 = O1 + (size_t)row * 256 + c8;
    u16x8 a = *(const u16x8*)p0;
    u16x8 c = *(const u16x8*)p1;
    u16x8 r;
    #pragma unroll
    for (int i = 0; i < 8; i++) r[i] = f2bf(w0 * bf2f(a[i]) + w1 * bf2f(c[i]));
    *(u16x8*)p0 = r;
}

// ---------------- host launch ----------------
extern "C" void kernel_launch(void* const* d_in, const int* in_sizes, int n_in,
                              void* d_out, int out_size, void* d_ws, size_t ws_size,
                              hipStream_t stream)
{
    const float* x   = (const float*)d_in[0];
    const float* Wq  = (const float*)d_in[1];
    const float* bq  = (const float*)d_in[2];
    const float* Wk  = (const float*)d_in[3];
    const float* bk  = (const float*)d_in[4];
    const float* Wv  = (const float*)d_in[5];
    const float* bv  = (const float*)d_in[6];
    const float* Wo  = (const float*)d_in[7];
    const float* bo  = (const float*)d_in[8];
    const float* gqs = (const float*)d_in[9];
    const float* gqb = (const float*)d_in[10];
    const float* gks = (const float*)d_in[11];
    const float* gkb = (const float*)d_in[12];
    const float* gvs = (const float*)d_in[13];
    const float* gvb = (const float*)d_in[14];

    const size_t BIGB = (size_t)NB * HWPX * CH * 2;          // 16 MB per bf16 buffer
    const size_t WTB  = 4 * 65536 * 2;                       // 512 KB
    const size_t BIASB = 4 * 256 * 4;                        // 4 KB
    const size_t MLB  = 2 * 32768 * 2 * 4;                   // 512 KB
    size_t need_base  = 4 * BIGB + WTB + BIASB;
    size_t need_split = need_base + BIGB + MLB;
    if (ws_size < need_base) return;

    char* w = (char*)d_ws;
    u16*  Xh   = (u16*)(w);                    // [B][p][c]; O-half0 after V proj
    u16*  Qt   = (u16*)(w + BIGB);
    u16*  Kt   = (u16*)(w + 2 * BIGB);
    u16*  Vc   = (u16*)(w + 3 * BIGB);
    u16*  Wt   = (u16*)(w + 4 * BIGB);
    float* bias = (float*)(w + 4 * BIGB + WTB);
    u16*  O1   = (u16*)(w + 4 * BIGB + WTB + BIASB);
    float* ML  = (float*)(w + 4 * BIGB + WTB + BIASB + BIGB);

    wprep<<<dim3(1024), dim3(256), 0, stream>>>(Wq, bq, gqs, gqb, Wk, bk, gks, gkb,
                                                Wv, bv, gvs, gvb, Wo, bo, Wt, bias);
    gn_kernel<<<dim3(1024), dim3(256), 0, stream>>>(x, Xh);

    gemm_nt<0><<<dim3(4, 512), dim3(256), 0, stream>>>(Xh, Wt,           bias,       Qt, nullptr, nullptr);
    gemm_nt<0><<<dim3(4, 512), dim3(256), 0, stream>>>(Xh, Wt + 65536,   bias + 256, Kt, nullptr, nullptr);
    gemm_nt<1><<<dim3(512, 4), dim3(256), 0, stream>>>(Wt + 131072, Xh,  bias + 512, Vc, nullptr, nullptr);

    if (ws_size >= need_split) {
        attn<2><<<dim3(512), dim3(256), 0, stream>>>(Qt, Kt, Vc, Xh, O1, ML);
        merge_halves<<<dim3(4096), dim3(256), 0, stream>>>(Xh, O1, ML);
    } else {
        attn<1><<<dim3(256), dim3(256), 0, stream>>>(Qt, Kt, Vc, Xh, nullptr, nullptr);
    }

    gemm_nt<2><<<dim3(512, 4), dim3(256), 0, stream>>>(Wt + 196608, Xh,  bias + 768, nullptr, (float*)d_out, x);
}

// Round 9
// 148.448 us; speedup vs baseline: 1.1406x; 1.1406x over previous
//
#include <hip/hip_runtime.h>
#include <stdint.h>

// B=32, C=256, H=W=32 (HW=1024), GROUPS=32, EPS=1e-5.
// K0 wprep : Wt[d][c] bf16 (gs/scale folded), bias folded. q-scale = log2e/16.
// K1 gn    : Xh[b][p][c] bf16.
// K2 gemm<0>: Q,K proj -> FP8 e4m3 [p][d], cols interleaved (d = n0+lr*4+nt) for
//             coalesced dword fp8 stores; same permutation for Q and K (dot invariant).
//    gemm<1>: V proj -> FP8 [c][p] (kv order natural, byte stores).
//    gemm<2>: final out = x + Wo^T O + bo (fp32), unchanged.
// K3 attn  : full-FP8 flash attn, mfma_f32_32x32x16_fp8_fp8 for QK and PV.
//            K/V LDS tiles 8KB each, dbuf = 32KB. NH=1, grid 256, 1 barrier/step.
//            Lane-local defer-max softmax; P packed to fp8 in-register (4 shfl).

#define NB 32
#define CH 256
#define HWPX 1024

typedef __bf16 bf16x8 __attribute__((ext_vector_type(8)));
typedef float f32x4 __attribute__((ext_vector_type(4)));
typedef float f32x16 __attribute__((ext_vector_type(16)));
typedef unsigned short u16;
typedef unsigned char u8;
typedef unsigned int u32;
typedef u16 u16x8 __attribute__((ext_vector_type(8)));
typedef u32 u32x2 __attribute__((ext_vector_type(2)));

__device__ __forceinline__ u16 f2bf(float f) {
    __bf16 h = (__bf16)f;
    return __builtin_bit_cast(u16, h);
}
__device__ __forceinline__ bf16x8 ldb8(const u16* p) {
    return __builtin_bit_cast(bf16x8, *(const u16x8*)p);
}
__device__ __forceinline__ u32 pkfp8(float a, float b, float c, float d) {
    int w = __builtin_amdgcn_cvt_pk_fp8_f32(a, b, 0, false);
    w = __builtin_amdgcn_cvt_pk_fp8_f32(c, d, w, true);
    return (u32)w;
}
__device__ __forceinline__ void gld_lds16(const u8* g, u8* l) {
    __builtin_amdgcn_global_load_lds(
        (const __attribute__((address_space(1))) void*)g,
        (__attribute__((address_space(3))) void*)l, 16, 0, 0);
}

// ---------------- K0: weight prep ----------------
__global__ __launch_bounds__(256) void wprep(
    const float* __restrict__ Wq, const float* __restrict__ bq,
    const float* __restrict__ gqs, const float* __restrict__ gqb,
    const float* __restrict__ Wk, const float* __restrict__ bk,
    const float* __restrict__ gks, const float* __restrict__ gkb,
    const float* __restrict__ Wv, const float* __restrict__ bv,
    const float* __restrict__ gvs, const float* __restrict__ gvb,
    const float* __restrict__ Wo, const float* __restrict__ bo,
    u16* __restrict__ Wt, float* __restrict__ bias)
{
    int m = blockIdx.x >> 8;
    int d = blockIdx.x & 255;
    int c = threadIdx.x;
    const float *W, *bb, *gs, *gb; float scale;
    const float QSC = 0.09016844005556021f;   // log2(e)/16
    if (m == 0)      { W = Wq; bb = bq; gs = gqs; gb = gqb; scale = QSC; }
    else if (m == 1) { W = Wk; bb = bk; gs = gks; gb = gkb; scale = 1.f; }
    else if (m == 2) { W = Wv; bb = bv; gs = gvs; gb = gvb; scale = 1.f; }
    else             { W = Wo; bb = bo; gs = nullptr; gb = nullptr; scale = 1.f; }
    float w   = W[c * 256 + d];
    float gsc = gs ? gs[c] : 1.f;
    float gbc = gb ? gb[c] : 0.f;
    Wt[((size_t)m << 16) + d * 256 + c] = f2bf(w * gsc * scale);
    __shared__ float red[256];
    red[c] = gbc * w;
    __syncthreads();
    for (int s = 128; s > 0; s >>= 1) { if (c < s) red[c] += red[c + s]; __syncthreads(); }
    if (c == 0) bias[m * 256 + d] = (bb[d] + red[0]) * scale;
}

// ---------------- K1: groupnorm ----------------
__global__ __launch_bounds__(256) void gn_kernel(const float* __restrict__ x,
                                                 u16* __restrict__ Xh)
{
    int blk = blockIdx.x;
    int b = blk >> 5, g = blk & 31;
    const float* base = x + (size_t)(b * 256 + g * 8) * 1024;
    int t = threadIdx.x;
    float s = 0.f, s2 = 0.f;
    for (int i = 0; i < 32; i++) { float v = base[t + i * 256]; s += v; s2 += v * v; }
    __shared__ float rs[256], rq[256];
    rs[t] = s; rq[t] = s2;
    __syncthreads();
    for (int k = 128; k > 0; k >>= 1) {
        if (t < k) { rs[t] += rs[t + k]; rq[t] += rq[t + k]; }
        __syncthreads();
    }
    float mu  = rs[0] * (1.f / 8192.f);
    float var = rq[0] * (1.f / 8192.f) - mu * mu;
    float rv  = rsqrtf(var + 1e-5f);
    u16* outp = Xh + (size_t)b * (HWPX * CH) + g * 8;
    for (int it = 0; it < 4; it++) {
        int p = t + it * 256;
        u16x8 tv;
        #pragma unroll
        for (int c2 = 0; c2 < 8; c2++) tv[c2] = f2bf((base[c2 * 1024 + p] - mu) * rv);
        *(u16x8*)(outp + (size_t)p * 256) = tv;
    }
}

// ---------------- K2/K4: NT GEMM, shared B-tile in LDS ----------------
// MODE0: fp8 out [m][256], col = n0 + lr*4 + nt (interleaved), dword stores.
// MODE1: fp8 out Vc[b][m][p], natural cols, byte stores.
// MODE2: fp32 out + residual.
template <int MODE>
__global__ __launch_bounds__(256) void gemm_nt(
    const u16* __restrict__ A, const u16* __restrict__ Bm,
    const float* __restrict__ bias,
    u8* __restrict__ C8, float* __restrict__ Cf,
    const float* __restrict__ xres)
{
    __shared__ __align__(16) u16 Bt[64 * 256];
    int tid = threadIdx.x;
    int lane = tid & 63, wave = tid >> 6;
    int m0 = blockIdx.y * 64 + wave * 16;
    int n0 = blockIdx.x * 64;

    #pragma unroll
    for (int i = 0; i < 8; i++) {
        int G = i * 256 + tid;
        int row = G >> 5, g = G & 31;
        const u16* src = Bm + (size_t)(n0 + row) * 256 + ((g ^ (row & 7)) << 3);
        gld_lds16((const u8*)src, (u8*)(Bt + (size_t)(i * 256 + wave * 64) * 8));
    }

    int lr = lane & 15, hk = lane >> 4, lk = hk * 8;
    const u16* Ap = A + (size_t)(m0 + lr) * 256 + lk;
    bf16x8 af[8];
    #pragma unroll
    for (int kk = 0; kk < 8; kk++) af[kk] = ldb8(Ap + kk * 32);

    __syncthreads();

    f32x4 acc[4] = {};
    #pragma unroll
    for (int kk = 0; kk < 8; kk++) {
        #pragma unroll
        for (int nt = 0; nt < 4; nt++) {
            int row = (MODE == 0) ? (lr * 4 + nt) : (nt * 16 + lr);
            int g = (kk * 4 + hk) ^ (row & 7);
            bf16x8 bf = ldb8(Bt + (size_t)(row * 32 + g) * 8);
            acc[nt] = __builtin_amdgcn_mfma_f32_16x16x32_bf16(af[kk], bf, acc[nt], 0, 0, 0);
        }
    }
    int rbase = m0 + (hk << 2);
    if (MODE == 0) {
        int colbase = n0 + lr * 4;
        #pragma unroll
        for (int j = 0; j < 4; j++) {
            int row = rbase + j;
            u32 w = pkfp8(acc[0][j] + bias[colbase],
                          acc[1][j] + bias[colbase + 1],
                          acc[2][j] + bias[colbase + 2],
                          acc[3][j] + bias[colbase + 3]);
            *(u32*)(C8 + (size_t)row * 256 + colbase) = w;
        }
    } else {
        #pragma unroll
        for (int nt = 0; nt < 4; nt++) {
            int col = n0 + nt * 16 + lr;
            int b = col >> 10, p = col & 1023;
            #pragma unroll
            for (int j = 0; j < 4; j++) {
                int row = rbase + j;
                float v = acc[nt][j] + bias[row];
                size_t off = (size_t)b * (CH * HWPX) + (size_t)row * 1024 + p;
                if (MODE == 1) {
                    int w = __builtin_amdgcn_cvt_pk_fp8_f32(v, v, 0, false);
                    C8[off] = (u8)(w & 0xff);
                } else {
                    Cf[off] = v + xres[off];
                }
            }
        }
    }
}

// ---------------- K3: full-FP8 flash attention, 32x32 MFMA, swapped QK ----------------
// grid 256 (1 block/CU), 4 waves x 32 q-rows, KV step 32, 32 steps.
// S^T = mfma(K, Q); lane owns q = q0+(lane&31); P packed to fp8 in-register.
__global__ __launch_bounds__(256, 1) void attn(
    const u8* __restrict__ Qf8, const u8* __restrict__ Kf8,
    const u8* __restrict__ Vf8, u16* __restrict__ O)
{
    __shared__ __align__(16) u8 Kbuf[2][32 * 256];   // 2 x 8 KB, granule(16B) ^= row&7
    __shared__ __align__(16) u8 Vbuf[2][256 * 32];   // 2 x 8 KB, granule ^= (c>>2)&1

    int tid = threadIdx.x;
    int lane = tid & 63, wave = tid >> 6;
    int bid = blockIdx.x;
    int b  = (bid & 7) * 4 + (bid >> 6);   // XCD x hosts batches 4x..4x+3
    int qb = (bid >> 3) & 7;
    int q0 = qb * 128 + wave * 32;

    const u8* Qb = Qf8 + (size_t)b * (HWPX * CH);
    const u8* Kb = Kf8 + (size_t)b * (HWPX * CH);
    const u8* Vb = Vf8 + (size_t)b * (CH * HWPX);

    int lq = lane & 31, hi = lane >> 5;
    int kswz = lq & 7;
    int vs1  = (lq >> 2) & 1;

    // staging source offsets (inverse-swizzled, LDS dest linear)
    int koff[2], voff[2];
    #pragma unroll
    for (int i = 0; i < 2; i++) {
        int G = i * 256 + tid;
        int kr = G >> 4, kg = G & 15;
        koff[i] = kr * 256 + ((kg ^ (kr & 7)) << 4);
        int vr = G >> 1, vg = G & 1;
        voff[i] = vr * 1024 + ((vg ^ ((vr >> 2) & 1)) << 4);
    }

    // Q fragments: qf[f] = Q[q0+lq][f*16 + hi*8 .. +7] (fp8, 8 bytes)
    long qf[16];
    #pragma unroll
    for (int f = 0; f < 16; f++)
        qf[f] = *(const long*)(Qb + (size_t)(q0 + lq) * 256 + f * 16 + hi * 8);

    f32x16 oa[8] = {};
    float m_run = -1e30f, l_run = 0.f;

    // prologue: stage tile 0
    #pragma unroll
    for (int i = 0; i < 2; i++)
        gld_lds16(Kb + koff[i], &Kbuf[0][0] + (size_t)(i * 256 + wave * 64) * 16);
    #pragma unroll
    for (int i = 0; i < 2; i++)
        gld_lds16(Vb + voff[i], &Vbuf[0][0] + (size_t)(i * 256 + wave * 64) * 16);
    __syncthreads();

    for (int t = 0; t < 32; ++t) {
        int cur = t & 1;
        if (t < 31) {
            const u8* ks = Kb + (size_t)(t + 1) * (32 * 256);
            const u8* vs = Vb + (t + 1) * 32;
            #pragma unroll
            for (int i = 0; i < 2; i++)
                gld_lds16(ks + koff[i], &Kbuf[cur ^ 1][0] + (size_t)(i * 256 + wave * 64) * 16);
            #pragma unroll
            for (int i = 0; i < 2; i++)
                gld_lds16(vs + voff[i], &Vbuf[cur ^ 1][0] + (size_t)(i * 256 + wave * 64) * 16);
        }

        // ---- QK^T (fp8): S^T tile 32kv x 32q, two accumulators ----
        const u8* kb = Kbuf[cur];
        f32x16 s0 = {}, s1 = {};
        #pragma unroll
        for (int ff = 0; ff < 8; ff++) {
            long k0 = *(const long*)(kb + (size_t)lq * 256 + (((2 * ff) ^ kswz) << 4) + hi * 8);
            s0 = __builtin_amdgcn_mfma_f32_32x32x16_fp8_fp8(k0, qf[2 * ff], s0, 0, 0, 0);
            long k1 = *(const long*)(kb + (size_t)lq * 256 + (((2 * ff + 1) ^ kswz) << 4) + hi * 8);
            s1 = __builtin_amdgcn_mfma_f32_32x32x16_fp8_fp8(k1, qf[2 * ff + 1], s1, 0, 0, 0);
        }
        float s[16];
        #pragma unroll
        for (int r = 0; r < 16; r++) s[r] = s0[r] + s1[r];

        // ---- lane-local defer-max softmax (log2 domain) ----
        float m01 = fmaxf(s[0], s[1]),   m23 = fmaxf(s[2], s[3]);
        float m45 = fmaxf(s[4], s[5]),   m67 = fmaxf(s[6], s[7]);
        float m89 = fmaxf(s[8], s[9]),   mab = fmaxf(s[10], s[11]);
        float mcd = fmaxf(s[12], s[13]), mef = fmaxf(s[14], s[15]);
        float mloc = fmaxf(fmaxf(fmaxf(m01, m23), fmaxf(m45, m67)),
                           fmaxf(fmaxf(m89, mab), fmaxf(mcd, mef)));
        if (!__all(mloc - m_run <= 4.f)) {          // rare: t==0 or max jumped
            float mo = fmaxf(mloc, __shfl_xor(mloc, 32));
            float mn = fmaxf(m_run, mo);
            float sc = exp2f(m_run - mn);
            m_run = mn;
            l_run *= sc;
            #pragma unroll
            for (int ct = 0; ct < 8; ct++) {
                #pragma unroll
                for (int r = 0; r < 16; r++) oa[ct][r] *= sc;
            }
        }
        float p[16];
        #pragma unroll
        for (int r = 0; r < 16; r++) p[r] = exp2f(s[r] - m_run);   // <= 2^4
        l_run += (((p[0]+p[1])+(p[2]+p[3]))+((p[4]+p[5])+(p[6]+p[7])))
               + (((p[8]+p[9])+(p[10]+p[11]))+((p[12]+p[13])+(p[14]+p[15])));

        // ---- pack P^T to fp8 B-fragments in-register ----
        // p[r] = P[kv=(r&3)+8*(r>>2)+4*hi][q=lq]
        u32 a  = pkfp8(p[0],  p[1],  p[2],  p[3]);   // kv 0..3   (+4hi)
        u32 bb = pkfp8(p[4],  p[5],  p[6],  p[7]);   // kv 8..11  (+4hi)
        u32 c  = pkfp8(p[8],  p[9],  p[10], p[11]);  // kv 16..19 (+4hi)
        u32 d  = pkfp8(p[12], p[13], p[14], p[15]);  // kv 24..27 (+4hi)
        u32 xa = (u32)__shfl_xor((int)a, 32),  xb = (u32)__shfl_xor((int)bb, 32);
        u32 xc = (u32)__shfl_xor((int)c, 32),  xd = (u32)__shfl_xor((int)d, 32);
        u32x2 f0 = { hi ? xb : a, hi ? bb : xa };    // chunk0: kv hi*8 + 0..7
        u32x2 f1 = { hi ? xd : c, hi ? d  : xc };    // chunk1: kv 16 + hi*8 + 0..7
        long p0 = __builtin_bit_cast(long, f0);
        long p1 = __builtin_bit_cast(long, f1);

        // ---- PV (fp8): oa[ct] += V^T(c,kv) * P^T(kv,q) ----
        const u8* vb = Vbuf[cur];
        #pragma unroll
        for (int ct = 0; ct < 8; ct++) {
            const u8* vrow = vb + (size_t)(32 * ct + lq) * 32 + hi * 8;
            long v0 = *(const long*)(vrow + (vs1 << 4));
            long v1 = *(const long*)(vrow + ((vs1 ^ 1) << 4));
            oa[ct] = __builtin_amdgcn_mfma_f32_32x32x16_fp8_fp8(v0, p0, oa[ct], 0, 0, 0);
            oa[ct] = __builtin_amdgcn_mfma_f32_32x32x16_fp8_fp8(v1, p1, oa[ct], 0, 0, 0);
        }
        __syncthreads();   // one barrier/step
    }

    float lt = l_run + __shfl_xor(l_run, 32);
    float rinv = 1.f / lt;
    u16* Ob = O + (size_t)b * (HWPX * CH) + (size_t)(q0 + lq) * 256;
    #pragma unroll
    for (int ct = 0; ct < 8; ct++) {
        #pragma unroll
        for (int rg = 0; rg < 4; rg++) {
            u16 st0 = f2bf(oa[ct][rg * 4 + 0] * rinv);
            u16 st1 = f2bf(oa[ct][rg * 4 + 1] * rinv);
            u16 st2 = f2bf(oa[ct][rg * 4 + 2] * rinv);
            u16 st3 = f2bf(oa[ct][rg * 4 + 3] * rinv);
            u16x8 dummy;
            u16* dst = Ob + 32 * ct + 8 * rg + 4 * hi;
            dst[0] = st0; dst[1] = st1; dst[2] = st2; dst[3] = st3;
            (void)dummy;
        }
    }
}

// ---------------- host launch ----------------
extern "C" void kernel_launch(void* const* d_in, const int* in_sizes, int n_in,
                              void* d_out, int out_size, void* d_ws, size_t ws_size,
                              hipStream_t stream)
{
    const float* x   = (const float*)d_in[0];
    const float* Wq  = (const float*)d_in[1];
    const float* bq  = (const float*)d_in[2];
    const float* Wk  = (const float*)d_in[3];
    const float* bk  = (const float*)d_in[4];
    const float* Wv  = (const float*)d_in[5];
    const float* bv  = (const float*)d_in[6];
    const float* Wo  = (const float*)d_in[7];
    const float* bo  = (const float*)d_in[8];
    const float* gqs = (const float*)d_in[9];
    const float* gqb = (const float*)d_in[10];
    const float* gks = (const float*)d_in[11];
    const float* gkb = (const float*)d_in[12];
    const float* gvs = (const float*)d_in[13];
    const float* gvb = (const float*)d_in[14];

    const size_t NEL  = (size_t)NB * HWPX * CH;   // 8388608
    const size_t XHB  = NEL * 2;                  // bf16 Xh / O buffer
    const size_t F8B  = NEL;                      // fp8 buffers
    const size_t WTB  = 4 * 65536 * 2;
    const size_t BIASB = 4 * 256 * 4;
    size_t need = XHB + 3 * F8B + WTB + BIASB;
    if (ws_size < need) return;

    char* w = (char*)d_ws;
    u16*  Xh   = (u16*)(w);                       // [B][p][c] bf16; O after V proj
    u8*   Qf8  = (u8*)(w + XHB);
    u8*   Kf8  = (u8*)(w + XHB + F8B);
    u8*   Vf8  = (u8*)(w + XHB + 2 * F8B);
    u16*  Wt   = (u16*)(w + XHB + 3 * F8B);
    float* bias = (float*)(w + XHB + 3 * F8B + WTB);

    wprep<<<dim3(1024), dim3(256), 0, stream>>>(Wq, bq, gqs, gqb, Wk, bk, gks, gkb,
                                                Wv, bv, gvs, gvb, Wo, bo, Wt, bias);
    gn_kernel<<<dim3(1024), dim3(256), 0, stream>>>(x, Xh);

    // Q,K -> fp8 [p][d] (interleaved cols)
    gemm_nt<0><<<dim3(4, 512), dim3(256), 0, stream>>>(Xh, Wt,           bias,       Qf8, nullptr, nullptr);
    gemm_nt<0><<<dim3(4, 512), dim3(256), 0, stream>>>(Xh, Wt + 65536,   bias + 256, Kf8, nullptr, nullptr);
    // V -> fp8 [c][p]
    gemm_nt<1><<<dim3(512, 4), dim3(256), 0, stream>>>(Wt + 131072, Xh,  bias + 512, Vf8, nullptr, nullptr);
    // attention (writes bf16 O into Xh; Xh dead after V proj)
    attn<<<dim3(256), dim3(256), 0, stream>>>(Qf8, Kf8, Vf8, Xh);
    // out = x + Wo^T O + bo
    gemm_nt<2><<<dim3(512, 4), dim3(256), 0, stream>>>(Wt + 196608, Xh,  bias + 768, nullptr, (float*)d_out, x);
}